// Round 2
// baseline (9248.431 us; speedup 1.0000x reference)
//
#include <hip/hip_runtime.h>
#include <hip/hip_bf16.h>

// Poolformer forward.
// Dead code proofs (reference quirks we exploit):
//  1. m_glob = triu(ones((32,31)), k=31-128=-97) is all-True -> ALL global keys
//     masked to -FLT_MAX -> softmax weight exactly 0. The global transformer
//     branch (g) never reaches the output: skip it entirely.
//  2. v2 = k2 in local_attn: the local attention VALUES are the KEYS.
//     The v-half of x@wkv is therefore dead too -> compute only the K half.

#define DIMM   768
#define SEQLEN 4096
#define NHEADS 12
#define DH     64
#define WWIN   128
#define NBUCK  32
#define NDEPTH 4
#define FFDIM  3072
#define NTOK   32000
#define NEG_MAX (-3.402823466e38f)

// ---------------- embed: h = token_emb[x] + pos_emb ----------------
__global__ __launch_bounds__(256) void embed_kernel(
    const int* __restrict__ x, const float* __restrict__ tok,
    const float* __restrict__ pos, float* __restrict__ h) {
  int row = blockIdx.x;
  int t = threadIdx.x;
  int tk = x[row];
  const float* te = tok + (size_t)tk * DIMM;
  const float* pe = pos + (size_t)row * DIMM;
  float* hr = h + (size_t)row * DIMM;
  hr[t]       = te[t]       + pe[t];
  hr[t + 256] = te[t + 256] + pe[t + 256];
  hr[t + 512] = te[t + 512] + pe[t + 512];
}

// ---------------- layernorm: one block per row (768 cols) ----------------
__global__ __launch_bounds__(256) void ln_kernel(
    const float* __restrict__ in, const float* __restrict__ gam,
    const float* __restrict__ bet, float* __restrict__ out) {
  int row = blockIdx.x;
  int t = threadIdx.x;
  const float* xr = in + (size_t)row * DIMM;
  float v0 = xr[t], v1 = xr[t + 256], v2 = xr[t + 512];
  float s  = v0 + v1 + v2;
  float s2 = v0 * v0 + v1 * v1 + v2 * v2;
  #pragma unroll
  for (int o = 32; o > 0; o >>= 1) {
    s  += __shfl_down(s, o);
    s2 += __shfl_down(s2, o);
  }
  __shared__ float red[2][4];
  int wid = t >> 6, lane = t & 63;
  if (lane == 0) { red[0][wid] = s; red[1][wid] = s2; }
  __syncthreads();
  if (t == 0) {
    float ts  = red[0][0] + red[0][1] + red[0][2] + red[0][3];
    float ts2 = red[1][0] + red[1][1] + red[1][2] + red[1][3];
    float mean = ts * (1.0f / DIMM);
    float var  = ts2 * (1.0f / DIMM) - mean * mean;
    red[0][0] = mean;
    red[1][0] = rsqrtf(var + 1e-5f);
  }
  __syncthreads();
  float mean = red[0][0], rstd = red[1][0];
  float* orow = out + (size_t)row * DIMM;
  orow[t]       = (v0 - mean) * rstd * gam[t]       + bet[t];
  orow[t + 256] = (v1 - mean) * rstd * gam[t + 256] + bet[t + 256];
  orow[t + 512] = (v2 - mean) * rstd * gam[t + 512] + bet[t + 512];
}

// ---------------- generic f32 GEMM: C = act(A@B + bias) + resid ----------------
// 128x128 block tile, BK=8, 256 threads, 8x8 per thread (split 4+4).
// B row stride = ldb; C/resid row stride = ldc. act: 0=none, 1=exact gelu.
#define BM 128
#define BN 128
#define BK 8
__global__ __launch_bounds__(256) void gemm_kernel(
    const float* __restrict__ A, const float* __restrict__ B,
    const float* __restrict__ bias, const float* __restrict__ resid,
    float* __restrict__ C, int M, int N, int K, int ldb, int ldc, int act) {
  __shared__ __align__(16) float As[BK][BM + 4];
  __shared__ __align__(16) float Bs[BK][BN + 4];
  int bm = blockIdx.y * BM, bn = blockIdx.x * BN;
  int tid = threadIdx.x;
  int tx = tid & 15, ty = tid >> 4;
  float acc[8][8];
  #pragma unroll
  for (int i = 0; i < 8; ++i)
    #pragma unroll
    for (int j = 0; j < 8; ++j) acc[i][j] = 0.f;

  for (int k0 = 0; k0 < K; k0 += BK) {
    #pragma unroll
    for (int l = 0; l < 4; ++l) {
      int e = tid + l * 256;
      int i = e >> 3, kk = e & 7;
      As[kk][i] = A[(size_t)(bm + i) * K + k0 + kk];
    }
    #pragma unroll
    for (int l = 0; l < 4; ++l) {
      int e = tid + l * 256;
      int kk = e >> 7, j = e & 127;
      Bs[kk][j] = B[(size_t)(k0 + kk) * ldb + bn + j];
    }
    __syncthreads();
    #pragma unroll
    for (int kk = 0; kk < BK; ++kk) {
      float4 a0 = *(const float4*)&As[kk][ty * 4];
      float4 a1 = *(const float4*)&As[kk][64 + ty * 4];
      float4 b0 = *(const float4*)&Bs[kk][tx * 4];
      float4 b1 = *(const float4*)&Bs[kk][64 + tx * 4];
      float a[8] = {a0.x, a0.y, a0.z, a0.w, a1.x, a1.y, a1.z, a1.w};
      float b[8] = {b0.x, b0.y, b0.z, b0.w, b1.x, b1.y, b1.z, b1.w};
      #pragma unroll
      for (int i = 0; i < 8; ++i)
        #pragma unroll
        for (int j = 0; j < 8; ++j) acc[i][j] += a[i] * b[j];
    }
    __syncthreads();
  }

  #pragma unroll
  for (int i = 0; i < 8; ++i) {
    int r = bm + ((i < 4) ? (ty * 4 + i) : (64 + ty * 4 + i - 4));
    #pragma unroll
    for (int j = 0; j < 8; ++j) {
      int c = bn + ((j < 4) ? (tx * 4 + j) : (64 + tx * 4 + j - 4));
      float v = acc[i][j];
      if (bias) v += bias[c];
      if (act == 1) v = 0.5f * v * (1.0f + erff(v * 0.70710678118654752f));
      if (resid) v += resid[(size_t)r * ldc + c];
      C[(size_t)r * ldc + c] = v;
    }
  }
}

// ---------------- local attention (values == keys) ----------------
// Block = (bucket w, head hd), 128 threads, thread t = query row t.
// Keys = [window w-1 (zeros for w==0), window w], causal: key j visible iff j <= t+128.
// Zero-pad keys for w==0 contribute logit 0 (kept in denominator, as reference).
__global__ __launch_bounds__(128) void local_attn_kernel(
    const float* __restrict__ Q, const float* __restrict__ Kb,
    float* __restrict__ CTX) {
  int w = blockIdx.x, hd = blockIdx.y;
  int t = threadIdx.x;
  __shared__ float qs[128][65];
  __shared__ float ks[32][65];

  for (int e = t; e < 128 * 64; e += 128) {
    int i = e >> 6, d = e & 63;
    qs[i][d] = Q[(size_t)(w * WWIN + i) * DIMM + hd * DH + d];
  }

  float m = NEG_MAX, denom = 0.f;
  float acc[64];
  #pragma unroll
  for (int d = 0; d < 64; ++d) acc[d] = 0.f;

  for (int c0 = 0; c0 < 256; c0 += 32) {
    __syncthreads();
    for (int e = t; e < 32 * 64; e += 128) {
      int jj = e >> 6, d = e & 63;
      int p = (w - 1) * WWIN + c0 + jj;  // token position of this key
      ks[jj][d] = (p >= 0) ? Kb[(size_t)p * DIMM + hd * DH + d] : 0.f;
    }
    __syncthreads();

    if (c0 <= t + 128) {
      float sv[32];
      float cmax = NEG_MAX;
      #pragma unroll
      for (int jj = 0; jj < 32; ++jj) {
        int j = c0 + jj;
        float s = 0.f;
        #pragma unroll
        for (int d = 0; d < 64; ++d) s += qs[t][d] * ks[jj][d];
        s *= 0.125f;
        bool vis = (j <= t + 128);
        sv[jj] = vis ? s : NEG_MAX;
        if (vis) cmax = fmaxf(cmax, s);
      }
      float mn = fmaxf(m, cmax);
      float scale = expf(m - mn);
      denom *= scale;
      #pragma unroll
      for (int d = 0; d < 64; ++d) acc[d] *= scale;
      #pragma unroll
      for (int jj = 0; jj < 32; ++jj) {
        if (sv[jj] != NEG_MAX) {
          float p = expf(sv[jj] - mn);
          denom += p;
          #pragma unroll
          for (int d = 0; d < 64; ++d) acc[d] += p * ks[jj][d];  // values == keys
        }
      }
      m = mn;
    }
  }
  float inv = 1.0f / denom;
  float* orow = CTX + (size_t)(w * WWIN + t) * DIMM + hd * DH;
  #pragma unroll
  for (int d = 0; d < 64; ++d) orow[d] = acc[d] * inv;
}

// ---------------- launch ----------------
extern "C" void kernel_launch(void* const* d_in, const int* in_sizes, int n_in,
                              void* d_out, int out_size, void* d_ws, size_t ws_size,
                              hipStream_t stream) {
  const int*   x         = (const int*)d_in[0];
  const float* token_emb = (const float*)d_in[1];
  const float* pos_emb   = (const float*)d_in[2];
  // d_in[3..14]: global-transformer params — dead code (fully masked), unused.
  const float* ln1_g = (const float*)d_in[15];
  const float* ln1_b = (const float*)d_in[16];
  const float* wq    = (const float*)d_in[17];
  const float* wkv   = (const float*)d_in[18];
  const float* wo    = (const float*)d_in[19];
  const float* bo    = (const float*)d_in[20];
  const float* ln2_g = (const float*)d_in[21];
  const float* ln2_b = (const float*)d_in[22];
  const float* w1    = (const float*)d_in[23];
  const float* b1    = (const float*)d_in[24];
  const float* w2    = (const float*)d_in[25];
  const float* b2    = (const float*)d_in[26];
  const float* f_ln_g = (const float*)d_in[27];
  const float* f_ln_b = (const float*)d_in[28];
  const float* w_logits = (const float*)d_in[29];
  const float* b_logits = (const float*)d_in[30];
  float* out = (float*)d_out;

  float* ws = (float*)d_ws;
  const size_t HN = (size_t)SEQLEN * DIMM;  // 3,145,728 floats
  float* h     = ws;            // persistent residual stream
  float* lnbuf = ws + HN;       // LN output
  float* scr   = ws + 2 * HN;   // 4*HN scratch region
  float* qb    = scr;           // 1*HN
  float* kb    = scr + HN;      // 1*HN (K projection only; V is dead)
  float* ctx   = scr + 2 * HN;  // 1*HN
  float* mid   = scr;           // 4*HN, aliases q/k/ctx AFTER attention consumed

  embed_kernel<<<SEQLEN, 256, 0, stream>>>(x, token_emb, pos_emb, h);

  for (int l = 0; l < NDEPTH; ++l) {
    ln_kernel<<<SEQLEN, 256, 0, stream>>>(h, ln1_g + l * DIMM, ln1_b + l * DIMM, lnbuf);
    gemm_kernel<<<dim3(DIMM / BN, SEQLEN / BM), 256, 0, stream>>>(
        lnbuf, wq + (size_t)l * DIMM * DIMM, nullptr, nullptr, qb,
        SEQLEN, DIMM, DIMM, DIMM, DIMM, 0);
    // K projection only: B = wkv[l][:, :768], row stride 1536.
    gemm_kernel<<<dim3(DIMM / BN, SEQLEN / BM), 256, 0, stream>>>(
        lnbuf, wkv + (size_t)l * DIMM * 2 * DIMM, nullptr, nullptr, kb,
        SEQLEN, DIMM, DIMM, 2 * DIMM, DIMM, 0);
    local_attn_kernel<<<dim3(NBUCK, NHEADS), 128, 0, stream>>>(qb, kb, ctx);
    gemm_kernel<<<dim3(DIMM / BN, SEQLEN / BM), 256, 0, stream>>>(
        ctx, wo + (size_t)l * DIMM * DIMM, bo + l * DIMM, h, h,
        SEQLEN, DIMM, DIMM, DIMM, DIMM, 0);
    ln_kernel<<<SEQLEN, 256, 0, stream>>>(h, ln2_g + l * DIMM, ln2_b + l * DIMM, lnbuf);
    gemm_kernel<<<dim3(FFDIM / BN, SEQLEN / BM), 256, 0, stream>>>(
        lnbuf, w1 + (size_t)l * DIMM * FFDIM, b1 + l * FFDIM, nullptr, mid,
        SEQLEN, FFDIM, DIMM, FFDIM, FFDIM, 1);
    gemm_kernel<<<dim3(DIMM / BN, SEQLEN / BM), 256, 0, stream>>>(
        mid, w2 + (size_t)l * FFDIM * DIMM, b2 + l * DIMM, h, h,
        SEQLEN, DIMM, FFDIM, DIMM, DIMM, 0);
  }

  ln_kernel<<<SEQLEN, 256, 0, stream>>>(h, f_ln_g, f_ln_b, lnbuf);
  gemm_kernel<<<dim3(NTOK / BN, SEQLEN / BM), 256, 0, stream>>>(
      lnbuf, w_logits, b_logits, nullptr, out, SEQLEN, NTOK, DIMM, NTOK, NTOK, 0);
}

// Round 3
// 3245.199 us; speedup vs baseline: 2.8499x; 2.8499x over previous
//
#include <hip/hip_runtime.h>
#include <hip/hip_bf16.h>

// Poolformer forward, bf16-MFMA GEMMs.
// Dead code proofs (reference quirks we exploit):
//  1. m_glob = triu(ones((32,31)), k=-97) is all-True -> ALL global keys masked
//     -> softmax weight exactly 0 -> global transformer branch never reaches
//     the output: skipped entirely.
//  2. v2 = k2 in local_attn: attention VALUES are the KEYS -> the v-half of
//     x@wkv is dead -> compute only the K half.
// Scratch strategy: d_ws holds only buffers live during the final logits GEMM
// (transposed logits weight + final LN output). All other intermediates live
// in d_out (rewritten fully by the logits GEMM every call -> deterministic).

#define DIMM   768
#define SEQLEN 4096
#define NHEADS 12
#define DH     64
#define WWIN   128
#define NBUCK  32
#define NDEPTH 4
#define FFDIM  3072
#define NTOK   32000
#define NEG_MAX (-3.402823466e38f)

typedef unsigned short u16;
typedef __attribute__((ext_vector_type(8))) short bf16x8;
typedef __attribute__((ext_vector_type(4))) float f32x4;

#define GLOAD16(gp, lp) \
  __builtin_amdgcn_global_load_lds((const __attribute__((address_space(1))) void*)(gp), \
                                   (__attribute__((address_space(3))) void*)(lp), 16, 0, 0)

__device__ __forceinline__ float b2f(u16 u) {
  union { unsigned int i; float f; } c; c.i = ((unsigned int)u) << 16; return c.f;
}

// ---------------- embed: h = token_emb[x] + pos_emb (f32) ----------------
__global__ __launch_bounds__(256) void embed_kernel(
    const int* __restrict__ x, const float* __restrict__ tok,
    const float* __restrict__ pos, float* __restrict__ h) {
  int row = blockIdx.x;
  int t = threadIdx.x;
  int tk = x[row];
  const float* te = tok + (size_t)tk * DIMM;
  const float* pe = pos + (size_t)row * DIMM;
  float* hr = h + (size_t)row * DIMM;
  hr[t]       = te[t]       + pe[t];
  hr[t + 256] = te[t + 256] + pe[t + 256];
  hr[t + 512] = te[t + 512] + pe[t + 512];
}

// ---------------- layernorm: f32 in, bf16 out ----------------
__global__ __launch_bounds__(256) void ln_kernel(
    const float* __restrict__ in, const float* __restrict__ gam,
    const float* __restrict__ bet, __hip_bfloat16* __restrict__ out) {
  int row = blockIdx.x;
  int t = threadIdx.x;
  const float* xr = in + (size_t)row * DIMM;
  float v0 = xr[t], v1 = xr[t + 256], v2 = xr[t + 512];
  float s  = v0 + v1 + v2;
  float s2 = v0 * v0 + v1 * v1 + v2 * v2;
  #pragma unroll
  for (int o = 32; o > 0; o >>= 1) {
    s  += __shfl_down(s, o);
    s2 += __shfl_down(s2, o);
  }
  __shared__ float red[2][4];
  int wid = t >> 6, lane = t & 63;
  if (lane == 0) { red[0][wid] = s; red[1][wid] = s2; }
  __syncthreads();
  if (t == 0) {
    float ts  = red[0][0] + red[0][1] + red[0][2] + red[0][3];
    float ts2 = red[1][0] + red[1][1] + red[1][2] + red[1][3];
    float mean = ts * (1.0f / DIMM);
    float var  = ts2 * (1.0f / DIMM) - mean * mean;
    red[0][0] = mean;
    red[1][0] = rsqrtf(var + 1e-5f);
  }
  __syncthreads();
  float mean = red[0][0], rstd = red[1][0];
  __hip_bfloat16* orow = out + (size_t)row * DIMM;
  orow[t]       = __float2bfloat16((v0 - mean) * rstd * gam[t]       + bet[t]);
  orow[t + 256] = __float2bfloat16((v1 - mean) * rstd * gam[t + 256] + bet[t + 256]);
  orow[t + 512] = __float2bfloat16((v2 - mean) * rstd * gam[t + 512] + bet[t + 512]);
}

// ---------------- weight prep: W[K][N] f32 -> Wt[N][K] bf16 ----------------
// grid = (N/32, K/32, layers); block = 256 (32x8).
__global__ __launch_bounds__(256) void wprep_kernel(
    const float* __restrict__ src, u16* __restrict__ dst,
    int ldsrc, int Krows, size_t sls, size_t dls) {
  __shared__ float tile[32][33];
  int l = blockIdx.z;
  int n0 = blockIdx.x * 32, k0 = blockIdx.y * 32;
  int tx = threadIdx.x & 31, ty = threadIdx.x >> 5;
  const float* s = src + (size_t)l * sls;
  u16* d = dst + (size_t)l * dls;
  #pragma unroll
  for (int i = 0; i < 4; ++i)
    tile[ty + i * 8][tx] = s[(size_t)(k0 + ty + i * 8) * ldsrc + n0 + tx];
  __syncthreads();
  #pragma unroll
  for (int i = 0; i < 4; ++i) {
    __hip_bfloat16 b = __float2bfloat16(tile[tx][ty + i * 8]);
    d[(size_t)(n0 + ty + i * 8) * Krows + k0 + tx] = *(u16*)&b;
  }
}

// ---------------- bf16 MFMA GEMM: C = act(A@Bt^T + bias) + resid ----------------
// A [M][K] bf16 row-major (lda=K); Bt [N][K] bf16 row-major (transposed weight).
// 128x128 tile, BK=32, 256 threads = 4 waves (2x2 of 64x64), 4x4 16x16x32 frags.
// grid = (N/128, M/128). act: 1 = exact gelu. cbf16: C dtype (else f32).
__global__ __launch_bounds__(256) void gemm_bf16(
    const u16* __restrict__ A, const u16* __restrict__ Bt,
    const float* __restrict__ bias, const float* __restrict__ resid,
    void* __restrict__ Cv, int K, int ldc, int act, int cbf16) {
  __shared__ u16 As[128 * 32];
  __shared__ u16 Bs[128 * 32];
  int tid = threadIdx.x;
  int wave = tid >> 6, lane = tid & 63;
  int bm = blockIdx.y * 128, bn = blockIdx.x * 128;
  int wm = (wave >> 1) * 64, wn = (wave & 1) * 64;
  int fr = lane & 15, fq = lane >> 4;

  f32x4 zero = {0.f, 0.f, 0.f, 0.f};
  f32x4 acc[4][4];
  #pragma unroll
  for (int i = 0; i < 4; ++i)
    #pragma unroll
    for (int j = 0; j < 4; ++j) acc[i][j] = zero;

  int r0 = tid >> 2;            // 0..63: row within half-tile
  int kb = (tid & 3) * 8;       // k element offset (16B granules)
  const u16* aptr = A + (size_t)(bm + r0) * K + kb;
  const u16* bptr = Bt + (size_t)(bn + r0) * K + kb;
  char* lA = (char*)As + (size_t)wave * 1024;  // wave-uniform LDS dest base
  char* lB = (char*)Bs + (size_t)wave * 1024;

  for (int k0 = 0; k0 < K; k0 += 32) {
    GLOAD16(aptr,                 lA);
    GLOAD16(aptr + (size_t)64 * K, lA + 4096);
    GLOAD16(bptr,                 lB);
    GLOAD16(bptr + (size_t)64 * K, lB + 4096);
    aptr += 32; bptr += 32;
    __syncthreads();
    bf16x8 af[4], bf[4];
    #pragma unroll
    for (int m = 0; m < 4; ++m)
      af[m] = *(const bf16x8*)&As[(wm + m * 16 + fr) * 32 + fq * 8];
    #pragma unroll
    for (int n = 0; n < 4; ++n)
      bf[n] = *(const bf16x8*)&Bs[(wn + n * 16 + fr) * 32 + fq * 8];
    #pragma unroll
    for (int m = 0; m < 4; ++m)
      #pragma unroll
      for (int n = 0; n < 4; ++n)
        acc[m][n] = __builtin_amdgcn_mfma_f32_16x16x32_bf16(af[m], bf[n], acc[m][n], 0, 0, 0);
    __syncthreads();
  }

  #pragma unroll
  for (int m = 0; m < 4; ++m) {
    #pragma unroll
    for (int rr = 0; rr < 4; ++rr) {
      int row = bm + wm + m * 16 + fq * 4 + rr;
      #pragma unroll
      for (int n = 0; n < 4; ++n) {
        int col = bn + wn + n * 16 + fr;
        float v = acc[m][n][rr];
        if (bias) v += bias[col];
        if (act) v = 0.5f * v * (1.0f + erff(v * 0.70710678118654752f));
        if (resid) v += resid[(size_t)row * ldc + col];
        if (cbf16) {
          __hip_bfloat16 b = __float2bfloat16(v);
          ((u16*)Cv)[(size_t)row * ldc + col] = *(u16*)&b;
        } else {
          ((float*)Cv)[(size_t)row * ldc + col] = v;
        }
      }
    }
  }
}

// ---------------- local attention (values == keys), bf16 in / bf16 out ----------------
__global__ __launch_bounds__(128) void local_attn_kernel(
    const u16* __restrict__ Q, const u16* __restrict__ Kb,
    u16* __restrict__ CTX) {
  int w = blockIdx.x, hd = blockIdx.y;
  int t = threadIdx.x;
  __shared__ float qs[128][65];
  __shared__ float ks[32][65];

  for (int e = t; e < 128 * 16; e += 128) {
    int i = e >> 4, d4 = (e & 15) << 2;
    ushort4 u = *(const ushort4*)&Q[(size_t)(w * WWIN + i) * DIMM + hd * DH + d4];
    qs[i][d4 + 0] = b2f(u.x); qs[i][d4 + 1] = b2f(u.y);
    qs[i][d4 + 2] = b2f(u.z); qs[i][d4 + 3] = b2f(u.w);
  }

  float m = NEG_MAX, denom = 0.f;
  float acc[64];
  #pragma unroll
  for (int d = 0; d < 64; ++d) acc[d] = 0.f;

  for (int c0 = 0; c0 < 256; c0 += 32) {
    __syncthreads();
    for (int e = t; e < 32 * 16; e += 128) {
      int jj = e >> 4, d4 = (e & 15) << 2;
      int p = (w - 1) * WWIN + c0 + jj;
      if (p >= 0) {
        ushort4 u = *(const ushort4*)&Kb[(size_t)p * DIMM + hd * DH + d4];
        ks[jj][d4 + 0] = b2f(u.x); ks[jj][d4 + 1] = b2f(u.y);
        ks[jj][d4 + 2] = b2f(u.z); ks[jj][d4 + 3] = b2f(u.w);
      } else {
        ks[jj][d4 + 0] = 0.f; ks[jj][d4 + 1] = 0.f;
        ks[jj][d4 + 2] = 0.f; ks[jj][d4 + 3] = 0.f;
      }
    }
    __syncthreads();

    if (c0 <= t + 128) {
      float sv[32];
      float cmax = NEG_MAX;
      #pragma unroll
      for (int jj = 0; jj < 32; ++jj) {
        int j = c0 + jj;
        float s = 0.f;
        #pragma unroll
        for (int d = 0; d < 64; ++d) s += qs[t][d] * ks[jj][d];
        s *= 0.125f;
        bool vis = (j <= t + 128);
        sv[jj] = vis ? s : NEG_MAX;
        if (vis) cmax = fmaxf(cmax, s);
      }
      float mn = fmaxf(m, cmax);
      float scale = expf(m - mn);
      denom *= scale;
      #pragma unroll
      for (int d = 0; d < 64; ++d) acc[d] *= scale;
      #pragma unroll
      for (int jj = 0; jj < 32; ++jj) {
        if (sv[jj] != NEG_MAX) {
          float p = expf(sv[jj] - mn);
          denom += p;
          #pragma unroll
          for (int d = 0; d < 64; ++d) acc[d] += p * ks[jj][d];  // values == keys
        }
      }
      m = mn;
    }
  }
  float inv = 1.0f / denom;
  u16* orow = CTX + (size_t)(w * WWIN + t) * DIMM + hd * DH;
  #pragma unroll
  for (int d = 0; d < 64; ++d) {
    __hip_bfloat16 b = __float2bfloat16(acc[d] * inv);
    orow[d] = *(u16*)&b;
  }
}

// ---------------- launch ----------------
extern "C" void kernel_launch(void* const* d_in, const int* in_sizes, int n_in,
                              void* d_out, int out_size, void* d_ws, size_t ws_size,
                              hipStream_t stream) {
  const int*   x         = (const int*)d_in[0];
  const float* token_emb = (const float*)d_in[1];
  const float* pos_emb   = (const float*)d_in[2];
  // d_in[3..14]: global-transformer params — dead (fully masked), unused.
  const float* ln1_g = (const float*)d_in[15];
  const float* ln1_b = (const float*)d_in[16];
  const float* wq    = (const float*)d_in[17];
  const float* wkv   = (const float*)d_in[18];
  const float* wo    = (const float*)d_in[19];
  const float* bo    = (const float*)d_in[20];
  const float* ln2_g = (const float*)d_in[21];
  const float* ln2_b = (const float*)d_in[22];
  const float* w1    = (const float*)d_in[23];
  const float* b1    = (const float*)d_in[24];
  const float* w2    = (const float*)d_in[25];
  const float* b2    = (const float*)d_in[26];
  const float* f_ln_g = (const float*)d_in[27];
  const float* f_ln_b = (const float*)d_in[28];
  const float* w_logits = (const float*)d_in[29];
  const float* b_logits = (const float*)d_in[30];
  float* out = (float*)d_out;

  // --- scratch in d_out (fully rewritten by final logits GEMM) ---
  char* ob = (char*)d_out;
  float* h   = (float*)(ob + 0);          // 12.58 MB f32 residual stream
  u16* qb    = (u16*)(ob + 12582912);     // 6.29 MB bf16
  u16* kb    = (u16*)(ob + 18874368);     // 6.29 MB bf16
  u16* ctx   = (u16*)(ob + 25165824);     // 6.29 MB bf16
  u16* mid   = (u16*)(ob + 31457280);     // 25.17 MB bf16 FFN mid
  u16* warena = (u16*)(ob + 56623104);    // 51.9 MB bf16 transposed layer weights
  const size_t WQ_SZ = (size_t)DIMM * DIMM;     // 589824
  const size_t W1_SZ = (size_t)DIMM * FFDIM;    // 2359296
  const size_t LW = 3 * WQ_SZ + 2 * W1_SZ;      // elems per layer
  u16* wq_t = warena;
  u16* wk_t = warena + WQ_SZ;
  u16* wo_t = warena + 2 * WQ_SZ;
  u16* w1_t = warena + 3 * WQ_SZ;
  u16* w2_t = warena + 3 * WQ_SZ + W1_SZ;

  // --- scratch in d_ws (live during final logits GEMM) ---
  u16* wlog_t = (u16*)d_ws;                                   // 49.15 MB
  __hip_bfloat16* lnbuf = (__hip_bfloat16*)((char*)d_ws + 49152000);  // 6.29 MB

  // ---- weight prep: transpose + bf16 convert ----
  wprep_kernel<<<dim3(24, 24, 4), 256, 0, stream>>>(wq,  wq_t, DIMM,   DIMM,  WQ_SZ,     LW);
  wprep_kernel<<<dim3(24, 24, 4), 256, 0, stream>>>(wkv, wk_t, 2*DIMM, DIMM,  2*WQ_SZ,   LW);
  wprep_kernel<<<dim3(24, 24, 4), 256, 0, stream>>>(wo,  wo_t, DIMM,   DIMM,  WQ_SZ,     LW);
  wprep_kernel<<<dim3(96, 24, 4), 256, 0, stream>>>(w1,  w1_t, FFDIM,  DIMM,  W1_SZ,     LW);
  wprep_kernel<<<dim3(24, 96, 4), 256, 0, stream>>>(w2,  w2_t, DIMM,   FFDIM, W1_SZ,     LW);
  wprep_kernel<<<dim3(1000, 24, 1), 256, 0, stream>>>(w_logits, wlog_t, NTOK, DIMM, 0, 0);

  embed_kernel<<<SEQLEN, 256, 0, stream>>>(x, token_emb, pos_emb, h);

  for (int l = 0; l < NDEPTH; ++l) {
    ln_kernel<<<SEQLEN, 256, 0, stream>>>(h, ln1_g + l * DIMM, ln1_b + l * DIMM, lnbuf);
    gemm_bf16<<<dim3(6, 32), 256, 0, stream>>>(
        (const u16*)lnbuf, wq_t + l * LW, nullptr, nullptr, qb, DIMM, DIMM, 0, 1);
    gemm_bf16<<<dim3(6, 32), 256, 0, stream>>>(
        (const u16*)lnbuf, wk_t + l * LW, nullptr, nullptr, kb, DIMM, DIMM, 0, 1);
    local_attn_kernel<<<dim3(NBUCK, NHEADS), 128, 0, stream>>>(qb, kb, ctx);
    gemm_bf16<<<dim3(6, 32), 256, 0, stream>>>(
        ctx, wo_t + l * LW, bo + l * DIMM, h, h, DIMM, DIMM, 0, 0);
    ln_kernel<<<SEQLEN, 256, 0, stream>>>(h, ln2_g + l * DIMM, ln2_b + l * DIMM, lnbuf);
    gemm_bf16<<<dim3(24, 32), 256, 0, stream>>>(
        (const u16*)lnbuf, w1_t + l * LW, b1 + l * FFDIM, nullptr, mid, DIMM, FFDIM, 1, 1);
    gemm_bf16<<<dim3(6, 32), 256, 0, stream>>>(
        mid, w2_t + l * LW, b2 + l * DIMM, h, h, FFDIM, DIMM, 0, 0);
  }

  ln_kernel<<<SEQLEN, 256, 0, stream>>>(h, f_ln_g, f_ln_b, lnbuf);
  gemm_bf16<<<dim3(NTOK / 128, 32), 256, 0, stream>>>(
      (const u16*)lnbuf, wlog_t, b_logits, nullptr, out, DIMM, NTOK, 0, 0);
}

// Round 4
// 2649.968 us; speedup vs baseline: 3.4900x; 1.2246x over previous
//
#include <hip/hip_runtime.h>
#include <hip/hip_bf16.h>

// Poolformer forward, bf16-MFMA GEMMs.
// Dead code proofs (reference quirks we exploit):
//  1. m_glob = triu(ones((32,31)), k=-97) is all-True -> ALL global keys masked
//     -> softmax weight exactly 0 -> global transformer branch skipped.
//  2. v2 = k2 in local_attn: attention VALUES are the KEYS -> v-half of x@wkv dead.
// Scratch: d_ws holds only buffers live during the final logits GEMM; all other
// intermediates live in d_out (fully rewritten by the logits GEMM every call).

#define DIMM   768
#define SEQLEN 4096
#define NHEADS 12
#define DH     64
#define WWIN   128
#define NBUCK  32
#define NDEPTH 4
#define FFDIM  3072
#define NTOK   32000
#define QKLD   1536
#define NEG_MAX (-3.402823466e38f)

typedef unsigned short u16;
typedef __attribute__((ext_vector_type(8))) short bf16x8;
typedef __attribute__((ext_vector_type(4))) float f32x4;

#define GLOAD16(gp, lp) \
  __builtin_amdgcn_global_load_lds((const __attribute__((address_space(1))) void*)(gp), \
                                   (__attribute__((address_space(3))) void*)(lp), 16, 0, 0)

__device__ __forceinline__ float b2f(u16 u) {
  union { unsigned int i; float f; } c; c.i = ((unsigned int)u) << 16; return c.f;
}

// ---------------- embed ----------------
__global__ __launch_bounds__(256) void embed_kernel(
    const int* __restrict__ x, const float* __restrict__ tok,
    const float* __restrict__ pos, float* __restrict__ h) {
  int row = blockIdx.x;
  int t = threadIdx.x;
  int tk = x[row];
  const float* te = tok + (size_t)tk * DIMM;
  const float* pe = pos + (size_t)row * DIMM;
  float* hr = h + (size_t)row * DIMM;
  hr[t]       = te[t]       + pe[t];
  hr[t + 256] = te[t + 256] + pe[t + 256];
  hr[t + 512] = te[t + 512] + pe[t + 512];
}

// ---------------- layernorm: f32 in, bf16 out ----------------
__global__ __launch_bounds__(256) void ln_kernel(
    const float* __restrict__ in, const float* __restrict__ gam,
    const float* __restrict__ bet, __hip_bfloat16* __restrict__ out) {
  int row = blockIdx.x;
  int t = threadIdx.x;
  const float* xr = in + (size_t)row * DIMM;
  float v0 = xr[t], v1 = xr[t + 256], v2 = xr[t + 512];
  float s  = v0 + v1 + v2;
  float s2 = v0 * v0 + v1 * v1 + v2 * v2;
  #pragma unroll
  for (int o = 32; o > 0; o >>= 1) {
    s  += __shfl_down(s, o);
    s2 += __shfl_down(s2, o);
  }
  __shared__ float red[2][4];
  int wid = t >> 6, lane = t & 63;
  if (lane == 0) { red[0][wid] = s; red[1][wid] = s2; }
  __syncthreads();
  if (t == 0) {
    float ts  = red[0][0] + red[0][1] + red[0][2] + red[0][3];
    float ts2 = red[1][0] + red[1][1] + red[1][2] + red[1][3];
    float mean = ts * (1.0f / DIMM);
    float var  = ts2 * (1.0f / DIMM) - mean * mean;
    red[0][0] = mean;
    red[1][0] = rsqrtf(var + 1e-5f);
  }
  __syncthreads();
  float mean = red[0][0], rstd = red[1][0];
  __hip_bfloat16* orow = out + (size_t)row * DIMM;
  orow[t]       = __float2bfloat16((v0 - mean) * rstd * gam[t]       + bet[t]);
  orow[t + 256] = __float2bfloat16((v1 - mean) * rstd * gam[t + 256] + bet[t + 256]);
  orow[t + 512] = __float2bfloat16((v2 - mean) * rstd * gam[t + 512] + bet[t + 512]);
}

// ---------------- weight prep: W[K][N] f32 -> Wt[N][K] bf16 ----------------
__global__ __launch_bounds__(256) void wprep_kernel(
    const float* __restrict__ src, u16* __restrict__ dst,
    int ldsrc, int Krows, size_t sls, size_t dls) {
  __shared__ float tile[32][33];
  int l = blockIdx.z;
  int n0 = blockIdx.x * 32, k0 = blockIdx.y * 32;
  int tx = threadIdx.x & 31, ty = threadIdx.x >> 5;
  const float* s = src + (size_t)l * sls;
  u16* d = dst + (size_t)l * dls;
  #pragma unroll
  for (int i = 0; i < 4; ++i)
    tile[ty + i * 8][tx] = s[(size_t)(k0 + ty + i * 8) * ldsrc + n0 + tx];
  __syncthreads();
  #pragma unroll
  for (int i = 0; i < 4; ++i) {
    __hip_bfloat16 b = __float2bfloat16(tile[tx][ty + i * 8]);
    d[(size_t)(n0 + ty + i * 8) * Krows + k0 + tx] = *(u16*)&b;
  }
}

// ---------------- bf16 MFMA GEMM: C = act(A@Bt^T + bias) + resid ----------------
// A [M][K] bf16 (lda=K); Bt [N][K] bf16. Tile TBM x 128, BK=32, 256 thr = 4 waves
// (2x2). TBM=128: wave 64x64 (4x4 frags). TBM=64: wave 32x64 (2x4 frags).
// LDS XOR-swizzle (slot ^= (row>>1)&3) on BOTH stage-source and read (rule #21).
// XCD-aware bijective block swizzle (requires nwg % 8 == 0).
template<int TBM>
__global__ __launch_bounds__(256) void gemm_bf16(
    const u16* __restrict__ A, const u16* __restrict__ Bt,
    const float* __restrict__ bias, const float* __restrict__ resid,
    void* __restrict__ Cv, int K, int ldc, int act, int cbf16) {
  constexpr int MFR = TBM / 32;  // A-frags per wave
  __shared__ u16 As[TBM * 32];
  __shared__ u16 Bs[128 * 32];
  int tid = threadIdx.x;
  int wave = tid >> 6, lane = tid & 63;

  int lin = blockIdx.y * gridDim.x + blockIdx.x;
  int cpx = (gridDim.x * gridDim.y) >> 3;
  int swz = (lin & 7) * cpx + (lin >> 3);
  int bx = swz % gridDim.x, by = swz / gridDim.x;

  int bm = by * TBM, bn = bx * 128;
  int wm = (wave >> 1) * (TBM / 2), wn = (wave & 1) * 64;
  int fr = lane & 15, fq = lane >> 4;

  f32x4 zero = {0.f, 0.f, 0.f, 0.f};
  f32x4 acc[MFR][4];
  #pragma unroll
  for (int i = 0; i < MFR; ++i)
    #pragma unroll
    for (int j = 0; j < 4; ++j) acc[i][j] = zero;

  int r0 = tid >> 2;                              // 0..63
  int kb = ((tid & 3) ^ ((r0 >> 1) & 3)) * 8;     // pre-swizzled source granule
  const u16* aptr = A + (size_t)(bm + r0) * K + kb;
  const u16* bptr = Bt + (size_t)(bn + r0) * K + kb;
  char* lA = (char*)As + (size_t)wave * 1024;
  char* lB = (char*)Bs + (size_t)wave * 1024;

  int sA = (fq ^ ((fr >> 1) & 3)) * 8;            // swizzled read granule offset

  for (int k0 = 0; k0 < K; k0 += 32) {
    GLOAD16(aptr, lA);
    if constexpr (TBM == 128) GLOAD16(aptr + (size_t)64 * K, lA + 4096);
    GLOAD16(bptr, lB);
    GLOAD16(bptr + (size_t)64 * K, lB + 4096);
    aptr += 32; bptr += 32;
    __syncthreads();
    bf16x8 af[MFR], bf[4];
    #pragma unroll
    for (int m = 0; m < MFR; ++m)
      af[m] = *(const bf16x8*)&As[(wm + m * 16 + fr) * 32 + sA];
    #pragma unroll
    for (int n = 0; n < 4; ++n)
      bf[n] = *(const bf16x8*)&Bs[(wn + n * 16 + fr) * 32 + sA];
    #pragma unroll
    for (int m = 0; m < MFR; ++m)
      #pragma unroll
      for (int n = 0; n < 4; ++n)
        acc[m][n] = __builtin_amdgcn_mfma_f32_16x16x32_bf16(af[m], bf[n], acc[m][n], 0, 0, 0);
    __syncthreads();
  }

  #pragma unroll
  for (int m = 0; m < MFR; ++m) {
    #pragma unroll
    for (int rr = 0; rr < 4; ++rr) {
      int row = bm + wm + m * 16 + fq * 4 + rr;
      #pragma unroll
      for (int n = 0; n < 4; ++n) {
        int col = bn + wn + n * 16 + fr;
        float v = acc[m][n][rr];
        if (bias) v += bias[col];
        if (act) v = 0.5f * v * (1.0f + erff(v * 0.70710678118654752f));
        if (resid) v += resid[(size_t)row * ldc + col];
        if (cbf16) {
          __hip_bfloat16 b = __float2bfloat16(v);
          ((u16*)Cv)[(size_t)row * ldc + col] = *(u16*)&b;
        } else {
          ((float*)Cv)[(size_t)row * ldc + col] = v;
        }
      }
    }
  }
}

// ---------------- local attention (values == keys) ----------------
// QK buffer [4096][1536]: cols 0..767 = Q, 768..1535 = K. Block = (bucket, head),
// 256 threads: thread = (row r = t>>1, d-half hf = t&1). Partial 32-dim dots
// combined via __shfl_xor(s,1). Causal: key j visible iff j <= r+128; bucket -1
// zero-keys kept in denominator (logit 0), as reference.
__global__ __launch_bounds__(256) void local_attn_kernel(
    const u16* __restrict__ QK, u16* __restrict__ CTX) {
  int w = blockIdx.x, hd = blockIdx.y;
  int t = threadIdx.x;
  int r = t >> 1, hf = t & 1;
  __shared__ float ks[32][65];

  float qr[32];
  const u16* qrow = QK + (size_t)(w * WWIN + r) * QKLD + hd * DH + hf * 32;
  #pragma unroll
  for (int i = 0; i < 8; ++i) {
    ushort4 u = *(const ushort4*)&qrow[i * 4];
    qr[i*4+0] = b2f(u.x); qr[i*4+1] = b2f(u.y);
    qr[i*4+2] = b2f(u.z); qr[i*4+3] = b2f(u.w);
  }

  float m = NEG_MAX, denom = 0.f;
  float acc[32];
  #pragma unroll
  for (int d = 0; d < 32; ++d) acc[d] = 0.f;

  for (int c0 = 0; c0 < 256; c0 += 32) {
    __syncthreads();
    for (int e = t; e < 512; e += 256) {
      int jj = e >> 4, d4 = (e & 15) << 2;
      int p = (w - 1) * WWIN + c0 + jj;
      if (p >= 0) {
        ushort4 u = *(const ushort4*)&QK[(size_t)p * QKLD + DIMM + hd * DH + d4];
        ks[jj][d4+0] = b2f(u.x); ks[jj][d4+1] = b2f(u.y);
        ks[jj][d4+2] = b2f(u.z); ks[jj][d4+3] = b2f(u.w);
      } else {
        ks[jj][d4+0] = 0.f; ks[jj][d4+1] = 0.f;
        ks[jj][d4+2] = 0.f; ks[jj][d4+3] = 0.f;
      }
    }
    __syncthreads();

    if (c0 <= r + 128) {
      float sv[32];
      float cmax = NEG_MAX;
      #pragma unroll
      for (int jj = 0; jj < 32; ++jj) {
        float s = 0.f;
        #pragma unroll
        for (int d = 0; d < 32; ++d) s += qr[d] * ks[jj][hf * 32 + d];
        s += __shfl_xor(s, 1);
        s *= 0.125f;
        bool vis = (c0 + jj <= r + 128);
        sv[jj] = vis ? s : NEG_MAX;
        if (vis) cmax = fmaxf(cmax, s);
      }
      float mn = fmaxf(m, cmax);
      float scale = expf(m - mn);
      denom *= scale;
      #pragma unroll
      for (int d = 0; d < 32; ++d) acc[d] *= scale;
      #pragma unroll
      for (int jj = 0; jj < 32; ++jj) {
        if (sv[jj] != NEG_MAX) {
          float p = expf(sv[jj] - mn);
          denom += p;
          #pragma unroll
          for (int d = 0; d < 32; ++d) acc[d] += p * ks[jj][hf * 32 + d];
        }
      }
      m = mn;
    }
  }
  float inv = 1.0f / denom;
  u16* orow = CTX + (size_t)(w * WWIN + r) * DIMM + hd * DH + hf * 32;
  #pragma unroll
  for (int d = 0; d < 32; ++d) {
    __hip_bfloat16 b = __float2bfloat16(acc[d] * inv);
    orow[d] = *(u16*)&b;
  }
}

// ---------------- launch ----------------
extern "C" void kernel_launch(void* const* d_in, const int* in_sizes, int n_in,
                              void* d_out, int out_size, void* d_ws, size_t ws_size,
                              hipStream_t stream) {
  const int*   x         = (const int*)d_in[0];
  const float* token_emb = (const float*)d_in[1];
  const float* pos_emb   = (const float*)d_in[2];
  // d_in[3..14]: global-transformer params — dead (fully masked), unused.
  const float* ln1_g = (const float*)d_in[15];
  const float* ln1_b = (const float*)d_in[16];
  const float* wq    = (const float*)d_in[17];
  const float* wkv   = (const float*)d_in[18];
  const float* wo    = (const float*)d_in[19];
  const float* bo    = (const float*)d_in[20];
  const float* ln2_g = (const float*)d_in[21];
  const float* ln2_b = (const float*)d_in[22];
  const float* w1    = (const float*)d_in[23];
  const float* b1    = (const float*)d_in[24];
  const float* w2    = (const float*)d_in[25];
  const float* b2    = (const float*)d_in[26];
  const float* f_ln_g = (const float*)d_in[27];
  const float* f_ln_b = (const float*)d_in[28];
  const float* w_logits = (const float*)d_in[29];
  const float* b_logits = (const float*)d_in[30];
  float* out = (float*)d_out;

  // --- scratch in d_out (fully rewritten by final logits GEMM) ---
  char* ob = (char*)d_out;
  float* h    = (float*)(ob + 0);          // 12.58 MB f32 residual stream
  u16* qk     = (u16*)(ob + 12582912);     // 12.58 MB bf16 [4096][1536]
  u16* ctx    = (u16*)(ob + 25165824);     // 6.29 MB bf16
  u16* mid    = (u16*)(ob + 31457280);     // 25.17 MB bf16 FFN mid
  u16* warena = (u16*)(ob + 56623104);     // 51.9 MB bf16 transposed weights
  const size_t WQ_SZ = (size_t)DIMM * DIMM;     // 589824
  const size_t W1_SZ = (size_t)DIMM * FFDIM;    // 2359296
  const size_t LW = 3 * WQ_SZ + 2 * W1_SZ;
  u16* qkw_t = warena;                 // [1536][768]: rows 0..767 = wq^T, 768.. = wk^T
  u16* wo_t  = warena + 2 * WQ_SZ;
  u16* w1_t  = warena + 3 * WQ_SZ;
  u16* w2_t  = warena + 3 * WQ_SZ + W1_SZ;

  // --- scratch in d_ws (live during final logits GEMM) ---
  u16* wlog_t = (u16*)d_ws;                                           // 49.15 MB
  __hip_bfloat16* lnbuf = (__hip_bfloat16*)((char*)d_ws + 49152000);  // 6.29 MB

  // ---- weight prep ----
  wprep_kernel<<<dim3(24, 24, 4), 256, 0, stream>>>(wq,  qkw_t,         DIMM,   DIMM,  WQ_SZ,   LW);
  wprep_kernel<<<dim3(24, 24, 4), 256, 0, stream>>>(wkv, qkw_t + WQ_SZ, 2*DIMM, DIMM,  2*WQ_SZ, LW);
  wprep_kernel<<<dim3(24, 24, 4), 256, 0, stream>>>(wo,  wo_t,          DIMM,   DIMM,  WQ_SZ,   LW);
  wprep_kernel<<<dim3(96, 24, 4), 256, 0, stream>>>(w1,  w1_t,          FFDIM,  DIMM,  W1_SZ,   LW);
  wprep_kernel<<<dim3(24, 96, 4), 256, 0, stream>>>(w2,  w2_t,          DIMM,   FFDIM, W1_SZ,   LW);
  wprep_kernel<<<dim3(1000, 24, 1), 256, 0, stream>>>(w_logits, wlog_t, NTOK, DIMM, 0, 0);

  embed_kernel<<<SEQLEN, 256, 0, stream>>>(x, token_emb, pos_emb, h);

  for (int l = 0; l < NDEPTH; ++l) {
    ln_kernel<<<SEQLEN, 256, 0, stream>>>(h, ln1_g + l * DIMM, ln1_b + l * DIMM, lnbuf);
    gemm_bf16<64><<<dim3(12, 64), 256, 0, stream>>>(
        (const u16*)lnbuf, qkw_t + l * LW, nullptr, nullptr, qk, DIMM, QKLD, 0, 1);
    local_attn_kernel<<<dim3(NBUCK, NHEADS), 256, 0, stream>>>(qk, ctx);
    gemm_bf16<64><<<dim3(6, 64), 256, 0, stream>>>(
        ctx, wo_t + l * LW, bo + l * DIMM, h, h, DIMM, DIMM, 0, 0);
    ln_kernel<<<SEQLEN, 256, 0, stream>>>(h, ln2_g + l * DIMM, ln2_b + l * DIMM, lnbuf);
    gemm_bf16<128><<<dim3(24, 32), 256, 0, stream>>>(
        (const u16*)lnbuf, w1_t + l * LW, b1 + l * FFDIM, nullptr, mid, DIMM, FFDIM, 1, 1);
    gemm_bf16<64><<<dim3(6, 64), 256, 0, stream>>>(
        mid, w2_t + l * LW, b2 + l * DIMM, h, h, FFDIM, DIMM, 0, 0);
  }

  ln_kernel<<<SEQLEN, 256, 0, stream>>>(h, f_ln_g, f_ln_b, lnbuf);
  gemm_bf16<128><<<dim3(NTOK / 128, 32), 256, 0, stream>>>(
      (const u16*)lnbuf, wlog_t, b_logits, nullptr, out, DIMM, NTOK, 0, 0);
}